// Round 8
// baseline (772.276 us; speedup 1.0000x reference)
//
#include <hip/hip_runtime.h>

// QuantumQLSTM on MI355X — R8: single-barrier sequential core.
// Structure (from R7): outs[t,b,:] = Hv[t,:] (b-independent). zx precompute
// (parallel) -> 1-block sequential rec (Hv table + final C) -> broadcast.
//
// R7 post-mortem: 2270 cyc/step = 2 barriers x vmcnt(0) drains (hv_tab store
// ack ~400, zx prefetch residual) + wave0-only matvec + 4-way LDS conflicts.
// R8: (1) matvec computed redundantly by EVERY wave (no cross-wave zh -> mid
// barrier deleted); Hbuf double-buffered by parity -> ONE barrier/step.
// (2) hv_tab store issued at top of NEXT step (full-step ack slack).
// (3) conflict-free matvec LDS mapping (ks*4+16i interleave).
// (4) zh broadcast via v_readlane (wave-uniform SGPRs), 12 used q's only.
//
// History: R1 4250 -> R2 2010 -> R3 1516 -> R4 1443 -> R5 1426 -> R6 FAILED
// -> R7 758 (rec 484) -> R8.

#define T_DIM 512
#define B_DIM 256
#define D_DIM 256
#define H_DIM 256
#define DH    512   // D + H
#define NG    16    // 4 gates * NQ(4)
#define PAD   260   // zx LDS row stride

__device__ __forceinline__ float fast_sigmoid(float x) {
    return 1.0f / (1.0f + __expf(-x));
}
__device__ __forceinline__ float fast_tanh(float x) {
    // |x| <= ~2.1 here (|C| <= 0.557/(1-0.731)); exp safe
    float e = __expf(2.0f * x);
    return (e - 1.0f) / (e + 1.0f);
}
__device__ __forceinline__ float fma4(float4 h, float4 w, float a) {
    return fmaf(h.x, w.x, fmaf(h.y, w.y, fmaf(h.z, w.z, fmaf(h.w, w.w, a))));
}
__device__ __forceinline__ float rl(float v, int lane) {
    return __uint_as_float(__builtin_amdgcn_readlane(__float_as_uint(v), lane));
}

// -------------------- zx precompute: zx[(t*B+b)*16+q] = b_q + x[t,b,:].Wx[q,:]
// (verified R1-R7 kernel, unchanged)
__global__ __launch_bounds__(256) void zx_kernel(
    const float* __restrict__ x,
    const float* __restrict__ Wf, const float* __restrict__ Wi,
    const float* __restrict__ Wu, const float* __restrict__ Wo,
    const float* __restrict__ bf, const float* __restrict__ bi,
    const float* __restrict__ bu, const float* __restrict__ bo,
    float* __restrict__ zx)
{
    __shared__ float Wl[NG][PAD];
    __shared__ float Xl[16][PAD];
    const int tid = threadIdx.x;

    for (int e = tid; e < NG * 64; e += 256) {
        int q16 = e >> 6, c4 = (e & 63) * 4;
        int g = q16 >> 2, qj = q16 & 3;
        const float* W = (g == 0) ? Wf : (g == 1) ? Wi : (g == 2) ? Wu : Wo;
        *(float4*)&Wl[q16][c4] = *(const float4*)(W + qj * DH + c4);
    }
    const long base = (long)blockIdx.x * 16 * D_DIM;
    for (int e = tid; e < 16 * 64; e += 256) {
        int r = e >> 6, c4 = (e & 63) * 4;
        *(float4*)&Xl[r][c4] = *(const float4*)(x + base + r * D_DIM + c4);
    }
    __syncthreads();

    const int q16 = tid & 15, r = tid >> 4;
    const int g = q16 >> 2, qj = q16 & 3;
    const float* bv = (g == 0) ? bf : (g == 1) ? bi : (g == 2) ? bu : bo;
    float acc = bv[qj];
    #pragma unroll 4
    for (int k = 0; k < D_DIM; k += 4) {
        float4 xv = *(float4*)&Xl[r][k];
        float4 wv = *(float4*)&Wl[q16][k];
        acc += xv.x * wv.x + xv.y * wv.y + xv.z * wv.z + xv.w * wv.w;
    }
    zx[(long)blockIdx.x * 256 + tid] = acc;
}

// -------------------- sequential core: ONE block, 256 threads, ONE barrier/step
__global__ __launch_bounds__(256) void rec_kernel(
    const float* __restrict__ Wf, const float* __restrict__ Wi,
    const float* __restrict__ Wu, const float* __restrict__ Wo,
    const float* __restrict__ phf, const float* __restrict__ phi,
    const float* __restrict__ phu, const float* __restrict__ pho,
    const float* __restrict__ zx,
    float* __restrict__ hv_tab,   // [T][H]; hv_tab[-H..-1] is a scratch pad row
    float* __restrict__ c_fin)    // [H]
{
    __shared__ float Hbuf[2][H_DIM];   // double-buffered Hv (parity by step)
    const int tid  = threadIdx.x;
    const int lane = tid & 63;
    const int q    = lane >> 2;        // 0..15 = gate*4 + j
    const int ks   = lane & 3;
    const int gate = q >> 2, j = q & 3;

    // Wh slice in regs; EVERY wave holds the full (q,ks) coverage -> redundant
    // matvec, no cross-wave zh exchange needed.
    const float* Wb = (gate == 0) ? Wf : (gate == 1) ? Wi : (gate == 2) ? Wu : Wo;
    const float* Wr = Wb + j * DH + 256;
    float4 Wreg[16];
    #pragma unroll
    for (int i = 0; i < 16; ++i) Wreg[i] = *(const float4*)(Wr + ks * 4 + 16 * i);

    const float pf1 = phf[1], pf2 = phf[2], pf3 = phf[3];
    const float pi1 = phi[1], pi2 = phi[2], pi3 = phi[3];
    const float pu1 = phu[1], pu2 = phu[2], pu3 = phu[3];
    const float po1 = pho[1], po2 = pho[2], po3 = pho[3];

    float C = 0.0f, Hprev = 0.0f;
    Hbuf[1][tid] = 0.0f;               // Hv[-1] = 0
    __syncthreads();

    // zx register double-buffer (depth 2, unroll x2)
    float4 za[4], zb[4];
    {
        const float4* p0 = (const float4*)(zx + (long)tid * NG);
        const float4* p1 = (const float4*)(zx + ((long)B_DIM + tid) * NG);
        #pragma unroll
        for (int i = 0; i < 4; ++i) { za[i] = p0[i]; zb[i] = p1[i]; }
    }

    auto step = [&](int t, float4* zr) {
        // early-issue global store: Hv[t-1] row (ack drains with ~full-step slack;
        // t=0 hits the scratch pad row at hv_tab[-H])
        hv_tab[(long)(t - 1) * H_DIM + tid] = Hprev;

        // ---- matvec: zh = Wh . Hv[t-1], redundant per wave, conflict-free LDS
        const float* Hp = Hbuf[(t + 1) & 1];
        float a0 = 0.f, a1 = 0.f, a2 = 0.f, a3 = 0.f;
        #pragma unroll
        for (int i = 0; i < 4; ++i) {
            float4 h0 = *(const float4*)&Hp[ks * 4 + 16 * (4 * i + 0)];
            float4 h1 = *(const float4*)&Hp[ks * 4 + 16 * (4 * i + 1)];
            float4 h2 = *(const float4*)&Hp[ks * 4 + 16 * (4 * i + 2)];
            float4 h3 = *(const float4*)&Hp[ks * 4 + 16 * (4 * i + 3)];
            a0 = fma4(h0, Wreg[4 * i + 0], a0);
            a1 = fma4(h1, Wreg[4 * i + 1], a1);
            a2 = fma4(h2, Wreg[4 * i + 2], a2);
            a3 = fma4(h3, Wreg[4 * i + 3], a3);
        }
        float acc = (a0 + a1) + (a2 + a3);
        acc += __shfl_xor(acc, 1);     // reduce ks (lane bits 0,1)
        acc += __shfl_xor(acc, 2);
        // wave-uniform zh via readlane; only the 12 q's used by the cos product
        const float zh1  = rl(acc,  4), zh2  = rl(acc,  8), zh3  = rl(acc, 12);
        const float zh5  = rl(acc, 20), zh6  = rl(acc, 24), zh7  = rl(acc, 28);
        const float zh9  = rl(acc, 36), zh10 = rl(acc, 40), zh11 = rl(acc, 44);
        const float zh13 = rl(acc, 52), zh14 = rl(acc, 56), zh15 = rl(acc, 60);

        // ---- per-h gates (h = tid)
        const float z1  = zr[0].y + zh1,  z2  = zr[0].z + zh2,  z3  = zr[0].w + zh3;
        const float z5  = zr[1].y + zh5,  z6  = zr[1].z + zh6,  z7  = zr[1].w + zh7;
        const float z9  = zr[2].y + zh9,  z10 = zr[2].z + zh10, z11 = zr[2].w + zh11;
        const float z13 = zr[3].y + zh13, z14 = zr[3].z + zh14, z15 = zr[3].w + zh15;

        // prefetch zx[t+2] now that zr is consumed (drains with ~transc slack)
        {
            const int tp = (t + 2 < T_DIM) ? (t + 2) : t;
            const float4* pp = (const float4*)(zx + ((long)tp * B_DIM + tid) * NG);
            #pragma unroll
            for (int i = 0; i < 4; ++i) zr[i] = pp[i];
        }

        const float pf  = __cosf(z1 + pf1) * __cosf(z2 + pf2) * __cosf(z3 + pf3);
        const float pi_ = __cosf(z5 + pi1) * __cosf(z6 + pi2) * __cosf(z7 + pi3);
        const float pu  = __cosf(z9 + pu1) * __cosf(z10 + pu2) * __cosf(z11 + pu3);
        const float po  = __cosf(z13 + po1) * __cosf(z14 + po2) * __cosf(z15 + po3);
        const float f  = fast_sigmoid(pf);
        const float ii = fast_sigmoid(pi_);
        const float u  = fast_tanh(pu);
        const float o  = fast_sigmoid(po);
        C = fmaf(f, C, ii * u);
        const float Hnew = o * fast_tanh(C);

        Hbuf[t & 1][tid] = Hnew;       // other-parity buffer: no WAR with readers
        Hprev = Hnew;
        __syncthreads();               // the ONE barrier: Hbuf write -> next matvec
    };

    for (int t = 0; t < T_DIM; t += 2) { step(t, za); step(t + 1, zb); }

    hv_tab[(long)(T_DIM - 1) * H_DIM + tid] = Hprev;
    c_fin[tid] = C;
}

// -------------------- broadcast: out[t,b,:] = Hv[t,:]; tails hx=Hv[511], cx=Cfin
__global__ __launch_bounds__(256) void bc_kernel(
    const float* __restrict__ hv_tab, const float* __restrict__ c_fin,
    float* __restrict__ out)
{
    const int blk  = blockIdx.x;
    const int w    = threadIdx.x >> 6;
    const int lane = threadIdx.x & 63;

    const float* src;
    long base;
    int rbase;
    if (blk < 4 * T_DIM) {
        const int t = blk >> 2;
        rbase = (blk & 3) * 64;
        src = hv_tab + (long)t * H_DIM;
        base = (long)t * (B_DIM * H_DIM);
    } else {
        const int k = blk - 4 * T_DIM;        // 0..7
        rbase = (k & 3) * 64;
        src = (k < 4) ? (hv_tab + (long)(T_DIM - 1) * H_DIM) : c_fin;
        base = (long)T_DIM * (B_DIM * H_DIM) + (k < 4 ? 0 : (long)B_DIM * H_DIM);
    }
    const float4 v = ((const float4*)src)[lane];
    #pragma unroll
    for (int it = 0; it < 16; ++it) {
        const int row = rbase + w + 4 * it;
        ((float4*)(out + base + (long)row * H_DIM))[lane] = v;
    }
}

extern "C" void kernel_launch(void* const* d_in, const int* in_sizes, int n_in,
                              void* d_out, int out_size, void* d_ws, size_t ws_size,
                              hipStream_t stream) {
    (void)in_sizes; (void)n_in; (void)out_size; (void)ws_size;
    const float* x   = (const float*)d_in[0];
    const float* Wf  = (const float*)d_in[1];
    const float* bf  = (const float*)d_in[2];
    const float* phf = (const float*)d_in[3];
    const float* Wi  = (const float*)d_in[4];
    const float* bi  = (const float*)d_in[5];
    const float* phi = (const float*)d_in[6];
    const float* Wu  = (const float*)d_in[7];
    const float* bu  = (const float*)d_in[8];
    const float* phu = (const float*)d_in[9];
    const float* Wo  = (const float*)d_in[10];
    const float* bo  = (const float*)d_in[11];
    const float* pho = (const float*)d_in[12];

    float* zx     = (float*)d_ws;                          // T*B*16 f = 8.39 MB
    float* hv_pad = zx + (size_t)T_DIM * B_DIM * NG;       // 256 f scratch (t=0 store)
    float* hv_tab = hv_pad + H_DIM;                        // T*H f = 512 KB
    float* c_fin  = hv_tab + (size_t)T_DIM * H_DIM;        // H f = 1 KB

    zx_kernel<<<(T_DIM * B_DIM) / 16, 256, 0, stream>>>(
        x, Wf, Wi, Wu, Wo, bf, bi, bu, bo, zx);

    rec_kernel<<<1, 256, 0, stream>>>(
        Wf, Wi, Wu, Wo, phf, phi, phu, pho, zx, hv_tab, c_fin);

    bc_kernel<<<4 * T_DIM + 8, 256, 0, stream>>>(hv_tab, c_fin, (float*)d_out);
}

// Round 9
// 752.261 us; speedup vs baseline: 1.0266x; 1.0266x over previous
//
#include <hip/hip_runtime.h>

// QuantumQLSTM on MI355X — R9: barrier WITHOUT vmcnt drain.
// Structure (R7/R8): outs[t,b,:] = Hv[t,:] (b-independent). zx precompute ->
// 1-block sequential rec (Hv table + final C) -> broadcast.
//
// R8 post-mortem: removing conflicts/extra-barrier/store-slack was NEUTRAL ->
// the critical path is the barrier's implicit `s_waitcnt vmcnt(0)`, which
// forces the in-step zx prefetch (LLC/HBM, ~600-900 cyc) to retire inside
// every step. R9: raw `s_waitcnt lgkmcnt(0); s_barrier` (inline asm) — LDS
// ordering only; vmem (zx loads, hv_tab stores) floats across steps with ~2
// steps of slack; compiler's static vmcnt(N) before zr consumption keeps
// correctness.
//
// History: R1 4250 -> R2 2010 -> R3 1516 -> R4 1443 -> R5 1426 -> R6 FAILED
// -> R7 758 (rec 484) -> R8 772 (rec 498, neutral) -> R9.

#define T_DIM 512
#define B_DIM 256
#define D_DIM 256
#define H_DIM 256
#define DH    512   // D + H
#define NG    16    // 4 gates * NQ(4)
#define PAD   260   // zx LDS row stride

__device__ __forceinline__ float fast_sigmoid(float x) {
    return 1.0f / (1.0f + __expf(-x));
}
__device__ __forceinline__ float fast_tanh(float x) {
    // |x| <= ~2.1 here (|C| <= 0.557/(1-0.731)); exp safe
    float e = __expf(2.0f * x);
    return (e - 1.0f) / (e + 1.0f);
}
__device__ __forceinline__ float fma4(float4 h, float4 w, float a) {
    return fmaf(h.x, w.x, fmaf(h.y, w.y, fmaf(h.z, w.z, fmaf(h.w, w.w, a))));
}
__device__ __forceinline__ float rl(float v, int lane) {
    return __uint_as_float(__builtin_amdgcn_readlane(__float_as_uint(v), lane));
}
// Barrier that drains ONLY the LDS pipe (no vmcnt): lets global loads/stores
// remain in flight across steps. "memory" clobber pins LDS op ordering.
__device__ __forceinline__ void lds_barrier() {
    __asm__ volatile("s_waitcnt lgkmcnt(0)\n\ts_barrier" ::: "memory");
}

// -------------------- zx precompute: zx[(t*B+b)*16+q] = b_q + x[t,b,:].Wx[q,:]
// (verified R1-R8 kernel, unchanged)
__global__ __launch_bounds__(256) void zx_kernel(
    const float* __restrict__ x,
    const float* __restrict__ Wf, const float* __restrict__ Wi,
    const float* __restrict__ Wu, const float* __restrict__ Wo,
    const float* __restrict__ bf, const float* __restrict__ bi,
    const float* __restrict__ bu, const float* __restrict__ bo,
    float* __restrict__ zx)
{
    __shared__ float Wl[NG][PAD];
    __shared__ float Xl[16][PAD];
    const int tid = threadIdx.x;

    for (int e = tid; e < NG * 64; e += 256) {
        int q16 = e >> 6, c4 = (e & 63) * 4;
        int g = q16 >> 2, qj = q16 & 3;
        const float* W = (g == 0) ? Wf : (g == 1) ? Wi : (g == 2) ? Wu : Wo;
        *(float4*)&Wl[q16][c4] = *(const float4*)(W + qj * DH + c4);
    }
    const long base = (long)blockIdx.x * 16 * D_DIM;
    for (int e = tid; e < 16 * 64; e += 256) {
        int r = e >> 6, c4 = (e & 63) * 4;
        *(float4*)&Xl[r][c4] = *(const float4*)(x + base + r * D_DIM + c4);
    }
    __syncthreads();

    const int q16 = tid & 15, r = tid >> 4;
    const int g = q16 >> 2, qj = q16 & 3;
    const float* bv = (g == 0) ? bf : (g == 1) ? bi : (g == 2) ? bu : bo;
    float acc = bv[qj];
    #pragma unroll 4
    for (int k = 0; k < D_DIM; k += 4) {
        float4 xv = *(float4*)&Xl[r][k];
        float4 wv = *(float4*)&Wl[q16][k];
        acc += xv.x * wv.x + xv.y * wv.y + xv.z * wv.z + xv.w * wv.w;
    }
    zx[(long)blockIdx.x * 256 + tid] = acc;
}

// -------------------- sequential core: ONE block, 256 threads, lds-only barrier
__global__ __launch_bounds__(256) void rec_kernel(
    const float* __restrict__ Wf, const float* __restrict__ Wi,
    const float* __restrict__ Wu, const float* __restrict__ Wo,
    const float* __restrict__ phf, const float* __restrict__ phi,
    const float* __restrict__ phu, const float* __restrict__ pho,
    const float* __restrict__ zx,
    float* __restrict__ hv_tab,   // [T][H]; hv_tab[-H..-1] is a scratch pad row
    float* __restrict__ c_fin)    // [H]
{
    __shared__ float Hbuf[2][H_DIM];   // double-buffered Hv (parity by step)
    const int tid  = threadIdx.x;
    const int lane = tid & 63;
    const int q    = lane >> 2;        // 0..15 = gate*4 + j
    const int ks   = lane & 3;
    const int gate = q >> 2, j = q & 3;

    // Wh slice in regs; EVERY wave holds full (q,ks) coverage -> redundant
    // matvec, no cross-wave zh exchange.
    const float* Wb = (gate == 0) ? Wf : (gate == 1) ? Wi : (gate == 2) ? Wu : Wo;
    const float* Wr = Wb + j * DH + 256;
    float4 Wreg[16];
    #pragma unroll
    for (int i = 0; i < 16; ++i) Wreg[i] = *(const float4*)(Wr + ks * 4 + 16 * i);

    const float pf1 = phf[1], pf2 = phf[2], pf3 = phf[3];
    const float pi1 = phi[1], pi2 = phi[2], pi3 = phi[3];
    const float pu1 = phu[1], pu2 = phu[2], pu3 = phu[3];
    const float po1 = pho[1], po2 = pho[2], po3 = pho[3];

    float C = 0.0f, Hprev = 0.0f;
    Hbuf[1][tid] = 0.0f;               // Hv[-1] = 0
    __syncthreads();

    // zx register double-buffer (depth 2, unroll x2)
    float4 za[4], zb[4];
    {
        const float4* p0 = (const float4*)(zx + (long)tid * NG);
        const float4* p1 = (const float4*)(zx + ((long)B_DIM + tid) * NG);
        #pragma unroll
        for (int i = 0; i < 4; ++i) { za[i] = p0[i]; zb[i] = p1[i]; }
    }

    auto step = [&](int t, float4* zr) {
        // early-issue global store of Hv[t-1] (acks float across steps now;
        // t=0 hits the scratch pad row at hv_tab[-H])
        hv_tab[(long)(t - 1) * H_DIM + tid] = Hprev;

        // ---- matvec: zh = Wh . Hv[t-1], redundant per wave, conflict-free LDS
        const float* Hp = Hbuf[(t + 1) & 1];
        float a0 = 0.f, a1 = 0.f, a2 = 0.f, a3 = 0.f;
        #pragma unroll
        for (int i = 0; i < 4; ++i) {
            float4 h0 = *(const float4*)&Hp[ks * 4 + 16 * (4 * i + 0)];
            float4 h1 = *(const float4*)&Hp[ks * 4 + 16 * (4 * i + 1)];
            float4 h2 = *(const float4*)&Hp[ks * 4 + 16 * (4 * i + 2)];
            float4 h3 = *(const float4*)&Hp[ks * 4 + 16 * (4 * i + 3)];
            a0 = fma4(h0, Wreg[4 * i + 0], a0);
            a1 = fma4(h1, Wreg[4 * i + 1], a1);
            a2 = fma4(h2, Wreg[4 * i + 2], a2);
            a3 = fma4(h3, Wreg[4 * i + 3], a3);
        }
        float acc = (a0 + a1) + (a2 + a3);
        acc += __shfl_xor(acc, 1);     // reduce ks (lane bits 0,1)
        acc += __shfl_xor(acc, 2);
        // wave-uniform zh via readlane; only the 12 q's used by the cos product
        const float zh1  = rl(acc,  4), zh2  = rl(acc,  8), zh3  = rl(acc, 12);
        const float zh5  = rl(acc, 20), zh6  = rl(acc, 24), zh7  = rl(acc, 28);
        const float zh9  = rl(acc, 36), zh10 = rl(acc, 40), zh11 = rl(acc, 44);
        const float zh13 = rl(acc, 52), zh14 = rl(acc, 56), zh15 = rl(acc, 60);

        // ---- per-h gates (h = tid)
        const float z1  = zr[0].y + zh1,  z2  = zr[0].z + zh2,  z3  = zr[0].w + zh3;
        const float z5  = zr[1].y + zh5,  z6  = zr[1].z + zh6,  z7  = zr[1].w + zh7;
        const float z9  = zr[2].y + zh9,  z10 = zr[2].z + zh10, z11 = zr[2].w + zh11;
        const float z13 = zr[3].y + zh13, z14 = zr[3].z + zh14, z15 = zr[3].w + zh15;

        // prefetch zx[t+2] now that zr is consumed (floats across steps)
        {
            const int tp = (t + 2 < T_DIM) ? (t + 2) : t;
            const float4* pp = (const float4*)(zx + ((long)tp * B_DIM + tid) * NG);
            #pragma unroll
            for (int i = 0; i < 4; ++i) zr[i] = pp[i];
        }

        const float pf  = __cosf(z1 + pf1) * __cosf(z2 + pf2) * __cosf(z3 + pf3);
        const float pi_ = __cosf(z5 + pi1) * __cosf(z6 + pi2) * __cosf(z7 + pi3);
        const float pu  = __cosf(z9 + pu1) * __cosf(z10 + pu2) * __cosf(z11 + pu3);
        const float po  = __cosf(z13 + po1) * __cosf(z14 + po2) * __cosf(z15 + po3);
        const float f  = fast_sigmoid(pf);
        const float ii = fast_sigmoid(pi_);
        const float u  = fast_tanh(pu);
        const float o  = fast_sigmoid(po);
        C = fmaf(f, C, ii * u);
        const float Hnew = o * fast_tanh(C);

        Hbuf[t & 1][tid] = Hnew;       // other-parity buffer: no WAR with readers
        Hprev = Hnew;
        lds_barrier();                 // lgkmcnt(0)+s_barrier ONLY — no vmcnt drain
    };

    for (int t = 0; t < T_DIM; t += 2) { step(t, za); step(t + 1, zb); }

    hv_tab[(long)(T_DIM - 1) * H_DIM + tid] = Hprev;
    c_fin[tid] = C;
}

// -------------------- broadcast: out[t,b,:] = Hv[t,:]; tails hx=Hv[511], cx=Cfin
__global__ __launch_bounds__(256) void bc_kernel(
    const float* __restrict__ hv_tab, const float* __restrict__ c_fin,
    float* __restrict__ out)
{
    const int blk  = blockIdx.x;
    const int w    = threadIdx.x >> 6;
    const int lane = threadIdx.x & 63;

    const float* src;
    long base;
    int rbase;
    if (blk < 4 * T_DIM) {
        const int t = blk >> 2;
        rbase = (blk & 3) * 64;
        src = hv_tab + (long)t * H_DIM;
        base = (long)t * (B_DIM * H_DIM);
    } else {
        const int k = blk - 4 * T_DIM;        // 0..7
        rbase = (k & 3) * 64;
        src = (k < 4) ? (hv_tab + (long)(T_DIM - 1) * H_DIM) : c_fin;
        base = (long)T_DIM * (B_DIM * H_DIM) + (k < 4 ? 0 : (long)B_DIM * H_DIM);
    }
    const float4 v = ((const float4*)src)[lane];
    #pragma unroll
    for (int it = 0; it < 16; ++it) {
        const int row = rbase + w + 4 * it;
        ((float4*)(out + base + (long)row * H_DIM))[lane] = v;
    }
}

extern "C" void kernel_launch(void* const* d_in, const int* in_sizes, int n_in,
                              void* d_out, int out_size, void* d_ws, size_t ws_size,
                              hipStream_t stream) {
    (void)in_sizes; (void)n_in; (void)out_size; (void)ws_size;
    const float* x   = (const float*)d_in[0];
    const float* Wf  = (const float*)d_in[1];
    const float* bf  = (const float*)d_in[2];
    const float* phf = (const float*)d_in[3];
    const float* Wi  = (const float*)d_in[4];
    const float* bi  = (const float*)d_in[5];
    const float* phi = (const float*)d_in[6];
    const float* Wu  = (const float*)d_in[7];
    const float* bu  = (const float*)d_in[8];
    const float* phu = (const float*)d_in[9];
    const float* Wo  = (const float*)d_in[10];
    const float* bo  = (const float*)d_in[11];
    const float* pho = (const float*)d_in[12];

    float* zx     = (float*)d_ws;                          // T*B*16 f = 8.39 MB
    float* hv_pad = zx + (size_t)T_DIM * B_DIM * NG;       // 256 f scratch (t=0 store)
    float* hv_tab = hv_pad + H_DIM;                        // T*H f = 512 KB
    float* c_fin  = hv_tab + (size_t)T_DIM * H_DIM;        // H f = 1 KB

    zx_kernel<<<(T_DIM * B_DIM) / 16, 256, 0, stream>>>(
        x, Wf, Wi, Wu, Wo, bf, bi, bu, bo, zx);

    rec_kernel<<<1, 256, 0, stream>>>(
        Wf, Wi, Wu, Wo, phf, phi, phu, pho, zx, hv_tab, c_fin);

    bc_kernel<<<4 * T_DIM + 8, 256, 0, stream>>>(hv_tab, c_fin, (float*)d_out);
}

// Round 10
// 744.497 us; speedup vs baseline: 1.0373x; 1.0104x over previous
//
#include <hip/hip_runtime.h>

// QuantumQLSTM on MI355X — R10: DPP matvec, near-zero LDS.
// Structure (R7+): outs[t,b,:] = Hv[t,:] (b-independent). zx precompute ->
// 1-block sequential rec (Hv table + final C) -> broadcast.
//
// R9 post-mortem: vmcnt-drain theory dead (R8/R9 both neutral). Real cost:
// LDS pipe is ONE per CU shared by 4 waves; redundant matvec = 64
// ds_read_b128 + 8 shfl per step ~= 850 cyc serialized pipe time.
// R10: lane owns h in {4L..4L+3} -> ONE ds_read_b128 per wave covers Hv;
// 12 Wh columns (j=0 rows are dead) in regs; wave-reduce via 6-level DPP add
// (pure VALU); readlane(63) broadcast. LDS inst/step: 76 -> 8.
// Also: phi folded into zx bias (12 fewer adds/step).
//
// History: R1 4250 -> R2 2010 -> R3 1516 -> R4 1443 -> R5 1426 -> R6 FAILED
// -> R7 758 (rec 484) -> R8 772 (rec 498) -> R9 752 (rec 477) -> R10.

#define T_DIM 512
#define B_DIM 256
#define D_DIM 256
#define H_DIM 256
#define DH    512   // D + H
#define NG    16    // 4 gates * NQ(4)
#define PAD   260   // zx LDS row stride

__device__ __forceinline__ float fast_sigmoid(float x) {
    return 1.0f / (1.0f + __expf(-x));
}
__device__ __forceinline__ float fast_tanh(float x) {
    // |x| <= ~2.1 here (|C| <= 0.557/(1-0.731)); exp safe
    float e = __expf(2.0f * x);
    return (e - 1.0f) / (e + 1.0f);
}
__device__ __forceinline__ float rl63(float v) {
    return __uint_as_float(__builtin_amdgcn_readlane(__float_as_uint(v), 63));
}
// x + dpp_mov(x): one level of the wave64 reduction, all in the VALU pipe.
template <int CTRL, int RM, int BM, bool BC>
__device__ __forceinline__ float dadd(float x) {
    return x + __int_as_float(
        __builtin_amdgcn_update_dpp(0, __float_as_int(x), CTRL, RM, BM, BC));
}
// full-wave sum; result valid in lane 63 (canonical GCN sequence)
__device__ __forceinline__ float wsum(float x) {
    x = dadd<0x111, 0xf, 0xf, true >(x);   // row_shr:1
    x = dadd<0x112, 0xf, 0xf, true >(x);   // row_shr:2
    x = dadd<0x114, 0xf, 0xf, true >(x);   // row_shr:4
    x = dadd<0x118, 0xf, 0xf, true >(x);   // row_shr:8  -> lane 15+16k = row sum
    x = dadd<0x142, 0xa, 0xf, false>(x);   // row_bcast:15 (rows 1,3)
    x = dadd<0x143, 0xc, 0xf, false>(x);   // row_bcast:31 (rows 2,3) -> lane63
    return x;
}
// Barrier draining ONLY the LDS pipe (no vmcnt): global loads/stores float.
__device__ __forceinline__ void lds_barrier() {
    __asm__ volatile("s_waitcnt lgkmcnt(0)\n\ts_barrier" ::: "memory");
}

// -------------------- zx precompute: zx[(t*B+b)*16+q] = b_q + phi_q + x.Wx[q,:]
// (phi folded into bias; j=0 entries carry phi[0] harmlessly — never used)
__global__ __launch_bounds__(256) void zx_kernel(
    const float* __restrict__ x,
    const float* __restrict__ Wf, const float* __restrict__ Wi,
    const float* __restrict__ Wu, const float* __restrict__ Wo,
    const float* __restrict__ bf, const float* __restrict__ bi,
    const float* __restrict__ bu, const float* __restrict__ bo,
    const float* __restrict__ phf, const float* __restrict__ phi,
    const float* __restrict__ phu, const float* __restrict__ pho,
    float* __restrict__ zx)
{
    __shared__ float Wl[NG][PAD];
    __shared__ float Xl[16][PAD];
    const int tid = threadIdx.x;

    for (int e = tid; e < NG * 64; e += 256) {
        int q16 = e >> 6, c4 = (e & 63) * 4;
        int g = q16 >> 2, qj = q16 & 3;
        const float* W = (g == 0) ? Wf : (g == 1) ? Wi : (g == 2) ? Wu : Wo;
        *(float4*)&Wl[q16][c4] = *(const float4*)(W + qj * DH + c4);
    }
    const long base = (long)blockIdx.x * 16 * D_DIM;
    for (int e = tid; e < 16 * 64; e += 256) {
        int r = e >> 6, c4 = (e & 63) * 4;
        *(float4*)&Xl[r][c4] = *(const float4*)(x + base + r * D_DIM + c4);
    }
    __syncthreads();

    const int q16 = tid & 15, r = tid >> 4;
    const int g = q16 >> 2, qj = q16 & 3;
    const float* bv = (g == 0) ? bf : (g == 1) ? bi : (g == 2) ? bu : bo;
    const float* pv = (g == 0) ? phf : (g == 1) ? phi : (g == 2) ? phu : pho;
    float acc = bv[qj] + pv[qj];
    #pragma unroll 4
    for (int k = 0; k < D_DIM; k += 4) {
        float4 xv = *(float4*)&Xl[r][k];
        float4 wv = *(float4*)&Wl[q16][k];
        acc += xv.x * wv.x + xv.y * wv.y + xv.z * wv.z + xv.w * wv.w;
    }
    zx[(long)blockIdx.x * 256 + tid] = acc;
}

// -------------------- sequential core: ONE block, 256 threads
// Matvec: redundant per wave; lane owns h = 4*lane..4*lane+3; 12 Wh columns in
// regs; DPP wave-reduction. ONE ds_read_b128 + ONE ds_write_b32 per wave/step.
__global__ __launch_bounds__(256) void rec_kernel(
    const float* __restrict__ Wf, const float* __restrict__ Wi,
    const float* __restrict__ Wu, const float* __restrict__ Wo,
    const float* __restrict__ zx,
    float* __restrict__ hv_tab,   // [T][H]; hv_tab[-H..-1] is a scratch pad row
    float* __restrict__ c_fin)    // [H]
{
    __shared__ float Hbuf[2][H_DIM];   // double-buffered Hv (parity by step)
    const int tid  = threadIdx.x;
    const int lane = tid & 63;
    const int l4   = lane * 4;

    // 12 Wh columns for this lane's 4 h's: Wreg[g*3+jj] = W_g[jj+1][256+l4..+3]
    float4 Wreg[12];
    #pragma unroll
    for (int jj = 0; jj < 3; ++jj) {
        Wreg[0 * 3 + jj] = *(const float4*)(Wf + (jj + 1) * DH + 256 + l4);
        Wreg[1 * 3 + jj] = *(const float4*)(Wi + (jj + 1) * DH + 256 + l4);
        Wreg[2 * 3 + jj] = *(const float4*)(Wu + (jj + 1) * DH + 256 + l4);
        Wreg[3 * 3 + jj] = *(const float4*)(Wo + (jj + 1) * DH + 256 + l4);
    }

    float C = 0.0f, Hprev = 0.0f;
    Hbuf[1][tid] = 0.0f;               // Hv[-1] = 0
    __syncthreads();

    // zx register double-buffer (depth 2, unroll x2); phi already folded in
    float4 za[4], zb[4];
    {
        const float4* p0 = (const float4*)(zx + (long)tid * NG);
        const float4* p1 = (const float4*)(zx + ((long)B_DIM + tid) * NG);
        #pragma unroll
        for (int i = 0; i < 4; ++i) { za[i] = p0[i]; zb[i] = p1[i]; }
    }

    auto step = [&](int t, float4* zr) {
        // early-issue global store of Hv[t-1] (acks float; t=0 -> scratch row)
        hv_tab[(long)(t - 1) * H_DIM + tid] = Hprev;

        // ---- matvec: zh[12] = Wh . Hv[t-1]
        const float4 Hv4 = *(const float4*)&Hbuf[(t + 1) & 1][l4];  // 1x b128
        float p[12];
        #pragma unroll
        for (int i = 0; i < 12; ++i) {
            const float4 w = Wreg[i];
            p[i] = fmaf(w.x, Hv4.x, fmaf(w.y, Hv4.y, fmaf(w.z, Hv4.z, w.w * Hv4.w)));
        }
        #pragma unroll
        for (int i = 0; i < 12; ++i) p[i] = wsum(p[i]);   // VALU-only reduce

        const float zf1 = zr[0].y + rl63(p[0]), zf2 = zr[0].z + rl63(p[1]), zf3 = zr[0].w + rl63(p[2]);
        const float zi1 = zr[1].y + rl63(p[3]), zi2 = zr[1].z + rl63(p[4]), zi3 = zr[1].w + rl63(p[5]);
        const float zu1 = zr[2].y + rl63(p[6]), zu2 = zr[2].z + rl63(p[7]), zu3 = zr[2].w + rl63(p[8]);
        const float zo1 = zr[3].y + rl63(p[9]), zo2 = zr[3].z + rl63(p[10]), zo3 = zr[3].w + rl63(p[11]);

        // prefetch zx[t+2] now that zr is consumed (floats across steps)
        {
            const int tp = (t + 2 < T_DIM) ? (t + 2) : t;
            const float4* pp = (const float4*)(zx + ((long)tp * B_DIM + tid) * NG);
            #pragma unroll
            for (int i = 0; i < 4; ++i) zr[i] = pp[i];
        }

        // ---- per-h gates (h = tid); phases already inside zx
        const float pf  = __cosf(zf1) * __cosf(zf2) * __cosf(zf3);
        const float pi_ = __cosf(zi1) * __cosf(zi2) * __cosf(zi3);
        const float pu  = __cosf(zu1) * __cosf(zu2) * __cosf(zu3);
        const float po  = __cosf(zo1) * __cosf(zo2) * __cosf(zo3);
        const float f  = fast_sigmoid(pf);
        const float ii = fast_sigmoid(pi_);
        const float u  = fast_tanh(pu);
        const float o  = fast_sigmoid(po);
        C = fmaf(f, C, ii * u);
        const float Hnew = o * fast_tanh(C);

        Hbuf[t & 1][tid] = Hnew;       // 1x ds_write_b32; other-parity buffer
        Hprev = Hnew;
        lds_barrier();                 // lgkmcnt(0)+s_barrier only
    };

    for (int t = 0; t < T_DIM; t += 2) { step(t, za); step(t + 1, zb); }

    hv_tab[(long)(T_DIM - 1) * H_DIM + tid] = Hprev;
    c_fin[tid] = C;
}

// -------------------- broadcast: out[t,b,:] = Hv[t,:]; tails hx=Hv[511], cx=Cfin
__global__ __launch_bounds__(256) void bc_kernel(
    const float* __restrict__ hv_tab, const float* __restrict__ c_fin,
    float* __restrict__ out)
{
    const int blk  = blockIdx.x;
    const int w    = threadIdx.x >> 6;
    const int lane = threadIdx.x & 63;

    const float* src;
    long base;
    int rbase;
    if (blk < 4 * T_DIM) {
        const int t = blk >> 2;
        rbase = (blk & 3) * 64;
        src = hv_tab + (long)t * H_DIM;
        base = (long)t * (B_DIM * H_DIM);
    } else {
        const int k = blk - 4 * T_DIM;        // 0..7
        rbase = (k & 3) * 64;
        src = (k < 4) ? (hv_tab + (long)(T_DIM - 1) * H_DIM) : c_fin;
        base = (long)T_DIM * (B_DIM * H_DIM) + (k < 4 ? 0 : (long)B_DIM * H_DIM);
    }
    const float4 v = ((const float4*)src)[lane];
    #pragma unroll
    for (int it = 0; it < 16; ++it) {
        const int row = rbase + w + 4 * it;
        ((float4*)(out + base + (long)row * H_DIM))[lane] = v;
    }
}

extern "C" void kernel_launch(void* const* d_in, const int* in_sizes, int n_in,
                              void* d_out, int out_size, void* d_ws, size_t ws_size,
                              hipStream_t stream) {
    (void)in_sizes; (void)n_in; (void)out_size; (void)ws_size;
    const float* x   = (const float*)d_in[0];
    const float* Wf  = (const float*)d_in[1];
    const float* bf  = (const float*)d_in[2];
    const float* phf = (const float*)d_in[3];
    const float* Wi  = (const float*)d_in[4];
    const float* bi  = (const float*)d_in[5];
    const float* phi = (const float*)d_in[6];
    const float* Wu  = (const float*)d_in[7];
    const float* bu  = (const float*)d_in[8];
    const float* phu = (const float*)d_in[9];
    const float* Wo  = (const float*)d_in[10];
    const float* bo  = (const float*)d_in[11];
    const float* pho = (const float*)d_in[12];

    float* zx     = (float*)d_ws;                          // T*B*16 f = 8.39 MB
    float* hv_pad = zx + (size_t)T_DIM * B_DIM * NG;       // 256 f scratch (t=0 store)
    float* hv_tab = hv_pad + H_DIM;                        // T*H f = 512 KB
    float* c_fin  = hv_tab + (size_t)T_DIM * H_DIM;        // H f = 1 KB

    zx_kernel<<<(T_DIM * B_DIM) / 16, 256, 0, stream>>>(
        x, Wf, Wi, Wu, Wo, bf, bi, bu, bo, phf, phi, phu, pho, zx);

    rec_kernel<<<1, 256, 0, stream>>>(
        Wf, Wi, Wu, Wo, zx, hv_tab, c_fin);

    bc_kernel<<<4 * T_DIM + 8, 256, 0, stream>>>(hv_tab, c_fin, (float*)d_out);
}

// Round 11
// 631.681 us; speedup vs baseline: 1.2226x; 1.1786x over previous
//
#include <hip/hip_runtime.h>

// QuantumQLSTM on MI355X — R11: 8 waves (2/SIMD), half-split gates.
// Structure (R7+): outs[t,b,:] = Hv[t,:] (b-independent). zx precompute ->
// 1-block sequential rec -> broadcast.
//
// R10 post-mortem: R8/R9/R10 all ~neutral. Invariant: ~300 instrs/wave at
// 1 wave/SIMD (lone-wave issue cadence ~4cyc + uncovered latency). R11:
// 512 thr = 8 waves = 2/SIMD; thread (h=tid>>1, half=tid&1) computes 2 of 4
// gates (6 cos not 12); partner exchange via __shfl_xor(,1) (intra-wave);
// matvec split: waves 0-5 x 2 columns -> zh LDS (+1 lds_barrier, ~free per
// R7/R8). ~100 instrs/wave/step, trans 22->12, 2 waves/SIMD to fill gaps.
//
// History: R1 4250 -> R2 2010 -> R3 1516 -> R4 1443 -> R5 1426 -> R6 FAILED
// -> R7 758 (rec 484) -> R8 772 (498) -> R9 752 (477) -> R10 744 (468) -> R11.

#define T_DIM 512
#define B_DIM 256
#define D_DIM 256
#define H_DIM 256
#define DH    512   // D + H
#define NG    16    // 4 gates * NQ(4)
#define PAD   260   // zx LDS row stride

__device__ __forceinline__ float fast_sigmoid(float x) {
    return 1.0f / (1.0f + __expf(-x));
}
__device__ __forceinline__ float fast_tanh(float x) {
    // |x| <= ~2.1 here (|C| <= 0.557/(1-0.731)); exp safe
    float e = __expf(2.0f * x);
    return (e - 1.0f) / (e + 1.0f);
}
// x + dpp_mov(x): one reduction level, VALU pipe.
template <int CTRL, int RM, int BM, bool BC>
__device__ __forceinline__ float dadd(float x) {
    return x + __int_as_float(
        __builtin_amdgcn_update_dpp(0, __float_as_int(x), CTRL, RM, BM, BC));
}
// full-wave sum; result valid in lane 63
__device__ __forceinline__ float wsum(float x) {
    x = dadd<0x111, 0xf, 0xf, true >(x);   // row_shr:1
    x = dadd<0x112, 0xf, 0xf, true >(x);   // row_shr:2
    x = dadd<0x114, 0xf, 0xf, true >(x);   // row_shr:4
    x = dadd<0x118, 0xf, 0xf, true >(x);   // row_shr:8
    x = dadd<0x142, 0xa, 0xf, false>(x);   // row_bcast:15
    x = dadd<0x143, 0xc, 0xf, false>(x);   // row_bcast:31 -> lane63
    return x;
}
// Barrier draining ONLY the LDS pipe (no vmcnt): global ops float across steps.
__device__ __forceinline__ void lds_barrier() {
    __asm__ volatile("s_waitcnt lgkmcnt(0)\n\ts_barrier" ::: "memory");
}

// -------------------- zx precompute: zx[(t*B+b)*16+q] = b_q + phi_q + x.Wx[q,:]
// (phi folded into bias; verified R10 kernel, unchanged)
__global__ __launch_bounds__(256) void zx_kernel(
    const float* __restrict__ x,
    const float* __restrict__ Wf, const float* __restrict__ Wi,
    const float* __restrict__ Wu, const float* __restrict__ Wo,
    const float* __restrict__ bf, const float* __restrict__ bi,
    const float* __restrict__ bu, const float* __restrict__ bo,
    const float* __restrict__ phf, const float* __restrict__ phi,
    const float* __restrict__ phu, const float* __restrict__ pho,
    float* __restrict__ zx)
{
    __shared__ float Wl[NG][PAD];
    __shared__ float Xl[16][PAD];
    const int tid = threadIdx.x;

    for (int e = tid; e < NG * 64; e += 256) {
        int q16 = e >> 6, c4 = (e & 63) * 4;
        int g = q16 >> 2, qj = q16 & 3;
        const float* W = (g == 0) ? Wf : (g == 1) ? Wi : (g == 2) ? Wu : Wo;
        *(float4*)&Wl[q16][c4] = *(const float4*)(W + qj * DH + c4);
    }
    const long base = (long)blockIdx.x * 16 * D_DIM;
    for (int e = tid; e < 16 * 64; e += 256) {
        int r = e >> 6, c4 = (e & 63) * 4;
        *(float4*)&Xl[r][c4] = *(const float4*)(x + base + r * D_DIM + c4);
    }
    __syncthreads();

    const int q16 = tid & 15, r = tid >> 4;
    const int g = q16 >> 2, qj = q16 & 3;
    const float* bv = (g == 0) ? bf : (g == 1) ? bi : (g == 2) ? bu : bo;
    const float* pv = (g == 0) ? phf : (g == 1) ? phi : (g == 2) ? phu : pho;
    float acc = bv[qj] + pv[qj];
    #pragma unroll 4
    for (int k = 0; k < D_DIM; k += 4) {
        float4 xv = *(float4*)&Xl[r][k];
        float4 wv = *(float4*)&Wl[q16][k];
        acc += xv.x * wv.x + xv.y * wv.y + xv.z * wv.z + xv.w * wv.w;
    }
    zx[(long)blockIdx.x * 256 + tid] = acc;
}

// -------------------- sequential core: ONE block, 512 threads (8 waves)
__global__ __launch_bounds__(512) void rec_kernel(
    const float* __restrict__ Wf, const float* __restrict__ Wi,
    const float* __restrict__ Wu, const float* __restrict__ Wo,
    const float* __restrict__ zx,
    float* __restrict__ hv_tab,   // [T][H]; hv_tab[-H..-1] is a scratch pad row
    float* __restrict__ c_fin)    // [H]
{
    __shared__ float Hbuf[2][H_DIM];       // double-buffered Hv
    __shared__ __align__(16) float zh_s[2][8];  // [half][6 used]
    const int tid  = threadIdx.x;          // 0..511
    const int lane = tid & 63;
    const int wv   = tid >> 6;             // wave 0..7
    const int h    = tid >> 1;             // 0..255
    const int half = tid & 1;              // 0: f,i   1: u,o
    const int l4   = lane * 4;

    // matvec columns for waves 0..5: cols cA=2w, cB=2w+1 (c = gate*3 + (j-1))
    float4 WA = make_float4(0,0,0,0), WB = WA;
    if (wv < 6) {
        const int cA = 2 * wv, cB = cA + 1;
        const int gA = cA / 3, jA = cA % 3 + 1;
        const int gB = cB / 3, jB = cB % 3 + 1;
        const float* WgA = (gA == 0) ? Wf : (gA == 1) ? Wi : (gA == 2) ? Wu : Wo;
        const float* WgB = (gB == 0) ? Wf : (gB == 1) ? Wi : (gB == 2) ? Wu : Wo;
        WA = *(const float4*)(WgA + jA * DH + 256 + l4);
        WB = *(const float4*)(WgB + jB * DH + 256 + l4);
    }

    float C = 0.0f, Hprev = 0.0f;
    if (tid < H_DIM) Hbuf[1][tid] = 0.0f;  // Hv[-1] = 0
    __syncthreads();

    // zx register double-buffer (depth 2): thread reads its half's 2 float4
    float4 za0, za1, zb0, zb1;
    {
        const float4* p0 = (const float4*)(zx + (long)h * NG) + half * 2;
        const float4* p1 = (const float4*)(zx + ((long)B_DIM + h) * NG) + half * 2;
        za0 = p0[0]; za1 = p0[1];
        zb0 = p1[0]; zb1 = p1[1];
    }

    auto step = [&](int t, float4& z0, float4& z1) {
        // early-issue global store of Hv[t-1] (half1 lanes; acks float)
        if (half) hv_tab[(long)(t - 1) * H_DIM + h] = Hprev;

        // ---- matvec: waves 0..5, 2 columns each
        if (wv < 6) {
            const float4 Hv4 = *(const float4*)&Hbuf[(t + 1) & 1][l4];
            float pA = fmaf(WA.x, Hv4.x, fmaf(WA.y, Hv4.y, fmaf(WA.z, Hv4.z, WA.w * Hv4.w)));
            float pB = fmaf(WB.x, Hv4.x, fmaf(WB.y, Hv4.y, fmaf(WB.z, Hv4.z, WB.w * Hv4.w)));
            pA = wsum(pA);
            pB = wsum(pB);
            if (lane == 63) {
                const int cA = 2 * wv;
                zh_s[cA / 6][cA % 6]       = pA;
                zh_s[(cA + 1) / 6][(cA + 1) % 6] = pB;
            }
        }
        lds_barrier();                      // zh + Hbuf(t-1) reads done below

        // ---- gates: this thread's 2 gates (half0: f,i ; half1: u,o)
        const float4 ZA = *(const float4*)&zh_s[half][0];
        const float2 ZB = *(const float2*)&zh_s[half][4];
        const float c1 = __cosf(z0.y + ZA.x), c2 = __cosf(z0.z + ZA.y), c3 = __cosf(z0.w + ZA.z);
        const float c4 = __cosf(z1.y + ZA.w), c5 = __cosf(z1.z + ZB.x), c6 = __cosf(z1.w + ZB.y);
        const float pA = c1 * c2 * c3, pB = c4 * c5 * c6;
        float gA, gB;
        if (half == 0) { gA = fast_sigmoid(pA); gB = fast_sigmoid(pB); }   // f, i
        else           { gA = fast_tanh(pA);    gB = fast_sigmoid(pB); }   // g, o
        const float oA = __shfl_xor(gA, 1);   // partner's first value
        const float oB = __shfl_xor(gB, 1);   // partner's second value
        const float f_ = half ? oA : gA;
        const float i_ = half ? oB : gB;
        const float g_ = half ? gA : oA;
        const float o_ = half ? gB : oB;

        // prefetch zx[t+2] (floats across steps)
        {
            const int tp = (t + 2 < T_DIM) ? (t + 2) : t;
            const float4* pp = (const float4*)(zx + ((long)tp * B_DIM + h) * NG) + half * 2;
            z0 = pp[0]; z1 = pp[1];
        }

        C = fmaf(f_, C, i_ * g_);             // both halves redundant, bit-identical
        const float Hnew = o_ * fast_tanh(C);
        if (half == 0) Hbuf[t & 1][h] = Hnew;
        Hprev = Hnew;
        lds_barrier();                        // Hbuf(t) + zh WAR for next step
    };

    for (int t = 0; t < T_DIM; t += 2) {
        step(t,     za0, za1);
        step(t + 1, zb0, zb1);
    }

    if (half) {
        hv_tab[(long)(T_DIM - 1) * H_DIM + h] = Hprev;
        c_fin[h] = C;
    }
}

// -------------------- broadcast: out[t,b,:] = Hv[t,:]; tails hx=Hv[511], cx=Cfin
__global__ __launch_bounds__(256) void bc_kernel(
    const float* __restrict__ hv_tab, const float* __restrict__ c_fin,
    float* __restrict__ out)
{
    const int blk  = blockIdx.x;
    const int w    = threadIdx.x >> 6;
    const int lane = threadIdx.x & 63;

    const float* src;
    long base;
    int rbase;
    if (blk < 4 * T_DIM) {
        const int t = blk >> 2;
        rbase = (blk & 3) * 64;
        src = hv_tab + (long)t * H_DIM;
        base = (long)t * (B_DIM * H_DIM);
    } else {
        const int k = blk - 4 * T_DIM;        // 0..7
        rbase = (k & 3) * 64;
        src = (k < 4) ? (hv_tab + (long)(T_DIM - 1) * H_DIM) : c_fin;
        base = (long)T_DIM * (B_DIM * H_DIM) + (k < 4 ? 0 : (long)B_DIM * H_DIM);
    }
    const float4 v = ((const float4*)src)[lane];
    #pragma unroll
    for (int it = 0; it < 16; ++it) {
        const int row = rbase + w + 4 * it;
        ((float4*)(out + base + (long)row * H_DIM))[lane] = v;
    }
}

extern "C" void kernel_launch(void* const* d_in, const int* in_sizes, int n_in,
                              void* d_out, int out_size, void* d_ws, size_t ws_size,
                              hipStream_t stream) {
    (void)in_sizes; (void)n_in; (void)out_size; (void)ws_size;
    const float* x   = (const float*)d_in[0];
    const float* Wf  = (const float*)d_in[1];
    const float* bf  = (const float*)d_in[2];
    const float* phf = (const float*)d_in[3];
    const float* Wi  = (const float*)d_in[4];
    const float* bi  = (const float*)d_in[5];
    const float* phi = (const float*)d_in[6];
    const float* Wu  = (const float*)d_in[7];
    const float* bu  = (const float*)d_in[8];
    const float* phu = (const float*)d_in[9];
    const float* Wo  = (const float*)d_in[10];
    const float* bo  = (const float*)d_in[11];
    const float* pho = (const float*)d_in[12];

    float* zx     = (float*)d_ws;                          // T*B*16 f = 8.39 MB
    float* hv_pad = zx + (size_t)T_DIM * B_DIM * NG;       // 256 f scratch (t=0 store)
    float* hv_tab = hv_pad + H_DIM;                        // T*H f = 512 KB
    float* c_fin  = hv_tab + (size_t)T_DIM * H_DIM;        // H f = 1 KB

    zx_kernel<<<(T_DIM * B_DIM) / 16, 256, 0, stream>>>(
        x, Wf, Wi, Wu, Wo, bf, bi, bu, bo, phf, phi, phu, pho, zx);

    rec_kernel<<<1, 512, 0, stream>>>(
        Wf, Wi, Wu, Wo, zx, hv_tab, c_fin);

    bc_kernel<<<4 * T_DIM + 8, 256, 0, stream>>>(hv_tab, c_fin, (float*)d_out);
}